// Round 2
// baseline (650.227 us; speedup 1.0000x reference)
//
#include <hip/hip_runtime.h>

#define N_BATCH 2048
#define HW 49          // H*W = 7*7
#define CCH 512        // channels
#define PADQ 52        // padded q-dim (multiple of 4): attn rows 16B-aligned

typedef float f4 __attribute__((ext_vector_type(4)));   // native vec: OK for nontemporal builtins

// ---------------------------------------------------------------------------
// Kernel A: pad-copy attn[n][p][q] -> attnP[n][p][qp], qp in [0,52), pad = 0.
// No transpose needed (BMM consumes rows). Reads and writes coalesced.
// Rows become 208 B (16B-aligned) so the BMM kernel reads them as uniform
// float4 -> s_load_dwordx4 on the scalar pipe.
// ---------------------------------------------------------------------------
__global__ __launch_bounds__(256) void pad_attn(
    const float* __restrict__ attn, float* __restrict__ attnP)
{
    const int n = blockIdx.x;
    const int tid = threadIdx.x;
    const float* a = attn + (size_t)n * (HW * HW);
    float* t = attnP + (size_t)n * (HW * PADQ);
    for (int j = tid; j < HW * PADQ; j += 256) {
        const int p = j / PADQ;          // magic-mul, cheap
        const int q = j - p * PADQ;
        t[j] = (q < HW) ? a[p * HW + q] : 0.0f;
    }
}

// ---------------------------------------------------------------------------
// Kernel B: 2 blocks per n (channel halves), 256 threads, 1 channel/thread.
// Phase 1: d[q] = D[n][q][c] into 52 regs (49 independent coalesced loads).
// Phase 2: per p, attn row p read as 13 wave-uniform float4 (s_loads) with a
//          1-row software prefetch; s = sum over q via 4 partial sums (breaks
//          the fmac latency chain); s streamed to ylds (stride-49 dwords =
//          conflict-free). No accumulator array -> ~70 VGPRs, no spill.
// Epilogue: flat float4 coalesced out = x + alpha*ylds (layouts match),
//           nontemporal stores to keep the write stream out of L3.
// ---------------------------------------------------------------------------
__global__ __launch_bounds__(256, 3) void fused_bmm_rowdot_add(
    const float* __restrict__ x, const float* __restrict__ D,
    const float* __restrict__ attnP, const float* __restrict__ alpha_p,
    float* __restrict__ out)
{
    __shared__ float ylds[256 * HW];   // 49 KB -> 3 blocks/CU
    const int bid = blockIdx.x;
    const int n   = bid >> 1;          // consecutive blocks share attnP rows (L2)
    const int h   = bid & 1;
    const int tid = threadIdx.x;
    const int c   = h * 256 + tid;

    // ---- phase 1: this thread's D column into registers ----
    float d[PADQ];
    d[PADQ - 3] = 0.0f; d[PADQ - 2] = 0.0f; d[PADQ - 1] = 0.0f;
    const float* Dn = D + (size_t)n * (HW * CCH) + c;
    #pragma unroll
    for (int q = 0; q < HW; ++q) d[q] = Dn[(size_t)q * CCH];

    // ---- phase 2: row-dot with 1-row prefetch ----
    const f4* Af = (const f4*)(attnP + (size_t)n * (HW * PADQ));

    f4 aC[PADQ / 4];
    #pragma unroll
    for (int j = 0; j < PADQ / 4; ++j) aC[j] = Af[j];

    #pragma unroll 1
    for (int p = 0; p < HW; ++p) {
        const int pn = (p + 1 < HW) ? (p + 1) : p;   // clamp: branch-free prefetch
        f4 aN[PADQ / 4];
        #pragma unroll
        for (int j = 0; j < PADQ / 4; ++j) aN[j] = Af[pn * (PADQ / 4) + j];

        float s0 = 0.f, s1 = 0.f, s2 = 0.f, s3 = 0.f;
        #pragma unroll
        for (int j = 0; j < PADQ / 4; ++j) {
            s0 += aC[j].x * d[4 * j + 0];
            s1 += aC[j].y * d[4 * j + 1];
            s2 += aC[j].z * d[4 * j + 2];
            s3 += aC[j].w * d[4 * j + 3];
        }
        ylds[tid * HW + p] = (s0 + s1) + (s2 + s3);

        #pragma unroll
        for (int j = 0; j < PADQ / 4; ++j) aC[j] = aN[j];
    }

    __syncthreads();

    // ---- epilogue: flat coalesced out = x + alpha*y ----
    const float alpha = alpha_p[0];
    const size_t base = (size_t)n * (CCH * HW) + (size_t)h * (256 * HW);
    const f4* x4 = (const f4*)(x + base);
    f4*       o4 = (f4*)(out + base);
    const f4* y4 = (const f4*)ylds;
    for (int i = tid; i < (256 * HW) / 4; i += 256) {
        const f4 xv = x4[i];
        const f4 yv = y4[i];
        f4 ov = xv + alpha * yv;
        __builtin_nontemporal_store(ov, &o4[i]);
    }
}

extern "C" void kernel_launch(void* const* d_in, const int* in_sizes, int n_in,
                              void* d_out, int out_size, void* d_ws, size_t ws_size,
                              hipStream_t stream) {
    const float* x     = (const float*)d_in[0];   // [2048,512,7,7]
    const float* attn  = (const float*)d_in[1];   // [2048,49,49]
    const float* Dm    = (const float*)d_in[2];   // [2048,49,512]
    const float* alpha = (const float*)d_in[3];   // [1]
    float* out = (float*)d_out;

    float* attnP = (float*)d_ws;   // 2048*49*52*4 = ~20.9 MB of ws

    pad_attn<<<N_BATCH, 256, 0, stream>>>(attn, attnP);
    fused_bmm_rowdot_add<<<N_BATCH * 2, 256, 0, stream>>>(x, Dm, attnP, alpha, out);
}

// Round 3
// 590.556 us; speedup vs baseline: 1.1010x; 1.1010x over previous
//
#include <hip/hip_runtime.h>

#define N_BATCH 2048
#define HW 49          // H*W = 7*7
#define CCH 512        // channels
#define PADQ 52        // padded q-dim (multiple of 4): attn rows 16B-aligned in LDS

typedef float f4 __attribute__((ext_vector_type(4)));

// ---------------------------------------------------------------------------
// Single fused kernel. 2 blocks per n (channel halves), 256 threads each,
// one channel per thread.
//
// Stage 0: attn[n] staged into LDS, rows padded 49 -> 52 floats (zeros), so
//          each row is 16B-aligned and read as 13 wave-uniform ds_read_b128
//          (same-address LDS access = hardware broadcast, conflict-free).
//          This kills the R2 scalar-pipe stall: SMEM s_loads return
//          out-of-order and force lgkmcnt(0) full drains (~3000 cyc/iter);
//          LDS broadcast is ~5 cyc/read on the DS pipe.
// Stage 1: d[q] = D[n][q][c] into 52 regs (49 independent coalesced loads).
// Stage 2: p-loop with 2-row ping-pong (no register-copy tail): dot via 4
//          partial sums; result streamed to ylds (stride-49 dwords = 2-way
//          bank aliasing = free).
// Epilogue: flat float4 coalesced out = x + alpha*ylds, nontemporal stores.
//
// LDS: 10,192 + 50,176 = 60,368 B -> 2 blocks/CU (8 waves). VGPR ~175 -> no
// spill at this occupancy. No workspace, no second kernel.
// ---------------------------------------------------------------------------
__global__ __launch_bounds__(256, 2) void fused_bmm_lds_bcast(
    const float* __restrict__ x, const float* __restrict__ D,
    const float* __restrict__ attn, const float* __restrict__ alpha_p,
    float* __restrict__ out)
{
    __shared__ float aT[HW * PADQ];     // 10,192 B, padded attn rows
    __shared__ float ylds[256 * HW];    // 50,176 B, y transpose staging

    const int bid = blockIdx.x;
    const int n   = bid >> 1;
    const int h   = bid & 1;
    const int tid = threadIdx.x;
    const int c   = h * 256 + tid;

    // ---- stage attn[n] -> LDS (padded rows, zeros in cols 49..51) ----
    const float* an = attn + (size_t)n * (HW * HW);
    for (int j = tid; j < HW * PADQ; j += 256) {
        const int r  = j / PADQ;            // magic-mul
        const int qq = j - r * PADQ;
        aT[j] = (qq < HW) ? an[r * HW + qq] : 0.0f;
    }

    // ---- this thread's D column into registers (overlaps attn staging) ----
    float d[PADQ];
    d[PADQ - 3] = 0.0f; d[PADQ - 2] = 0.0f; d[PADQ - 1] = 0.0f;
    const float* Dn = D + (size_t)n * (HW * CCH) + c;
    #pragma unroll
    for (int q = 0; q < HW; ++q) d[q] = Dn[(size_t)q * CCH];

    __syncthreads();

    const f4* Af = (const f4*)aT;       // row p = Af[p*13 .. p*13+12]

#define DOT(BUF, PP)                                                  \
    do {                                                              \
        float s0 = 0.f, s1 = 0.f, s2 = 0.f, s3 = 0.f;                 \
        _Pragma("unroll")                                             \
        for (int j = 0; j < PADQ / 4; ++j) {                          \
            s0 += BUF[j].x * d[4 * j + 0];                            \
            s1 += BUF[j].y * d[4 * j + 1];                            \
            s2 += BUF[j].z * d[4 * j + 2];                            \
            s3 += BUF[j].w * d[4 * j + 3];                            \
        }                                                             \
        ylds[tid * HW + (PP)] = (s0 + s1) + (s2 + s3);                \
    } while (0)

    f4 Abuf[PADQ / 4], Bbuf[PADQ / 4];
    #pragma unroll
    for (int j = 0; j < PADQ / 4; ++j) Abuf[j] = Af[j];   // row 0

    // rows 0..47 in ping-pong pairs; row 48 as tail (loaded at p=46)
    #pragma unroll 1
    for (int p = 0; p < HW - 1; p += 2) {
        #pragma unroll
        for (int j = 0; j < PADQ / 4; ++j) Bbuf[j] = Af[(p + 1) * (PADQ / 4) + j];
        DOT(Abuf, p);
        #pragma unroll
        for (int j = 0; j < PADQ / 4; ++j) Abuf[j] = Af[(p + 2) * (PADQ / 4) + j];
        DOT(Bbuf, p + 1);
    }
    DOT(Abuf, HW - 1);
#undef DOT

    __syncthreads();

    // ---- epilogue: flat coalesced out = x + alpha*y ----
    const float alpha = alpha_p[0];
    const size_t base = (size_t)n * (CCH * HW) + (size_t)h * (256 * HW);
    const f4* x4 = (const f4*)(x + base);
    f4*       o4 = (f4*)(out + base);
    const f4* y4 = (const f4*)ylds;
    for (int i = tid; i < (256 * HW) / 4; i += 256) {
        const f4 xv = x4[i];
        const f4 yv = y4[i];
        f4 ov = xv + alpha * yv;
        __builtin_nontemporal_store(ov, &o4[i]);
    }
}

extern "C" void kernel_launch(void* const* d_in, const int* in_sizes, int n_in,
                              void* d_out, int out_size, void* d_ws, size_t ws_size,
                              hipStream_t stream) {
    const float* x     = (const float*)d_in[0];   // [2048,512,7,7]
    const float* attn  = (const float*)d_in[1];   // [2048,49,49]
    const float* Dm    = (const float*)d_in[2];   // [2048,49,512]
    const float* alpha = (const float*)d_in[3];   // [1]
    float* out = (float*)d_out;
    (void)d_ws; (void)ws_size;

    fused_bmm_lds_bcast<<<N_BATCH * 2, 256, 0, stream>>>(x, Dm, attn, alpha, out);
}